// Round 7
// baseline (215.933 us; speedup 1.0000x reference)
//
#include <hip/hip_runtime.h>
#include <math.h>

// B=4, S=4096, D=2048, E=64, K=2
#define NTOK    16384
#define DDIM    2048
#define NEXP    64
#define PSTRIDE (NTOK * NEXP)      // floats per partial/output plane
#define KSPLIT  4
#define KRANGE  512                // k per block
#define NPH     16                 // phases of 32 k
#define TOKB    128                // tokens per block
#define WSLICE  8192               // W slice bytes: 2 planes x 64 e x 32 k x 2 B
#define PART_OFF (1 << 20)         // partials at d_ws + 1 MB

#define AS1 __attribute__((address_space(1)))
#define AS3 __attribute__((address_space(3)))

typedef _Float16 half8   __attribute__((ext_vector_type(8)));
typedef float    floatx4 __attribute__((ext_vector_type(4)));

// ---------------------------------------------------------------------------
// W (fp32 [64][2048]) -> d_ws: 64 slices (32 k each) of 8 KB, linear-DMA
// order with XOR chunk swizzle: slice p, chunk L = plane*256 + e*4 + c',
// holding source k-chunk c = c' ^ (e&3), k = p*32 + c*8.
// hi plane = (f16)w, lo = (f16)((w-hi)*2048).
// ---------------------------------------------------------------------------
__global__ __launch_bounds__(256) void wconv_kernel(
    const float* __restrict__ W, _Float16* __restrict__ ws)
{
    const int g     = blockIdx.x * 256 + threadIdx.x;   // 32768 chunks
    const int p     = g >> 9;          // slice 0..63
    const int L     = g & 511;
    const int plane = L >> 8;
    const int e     = (L >> 2) & 63;
    const int cp    = L & 3;
    const int c     = cp ^ (e & 3);
    const int k     = (p << 5) + (c << 3);

    const float* src = &W[(size_t)e * DDIM + k];
    floatx4 w0 = *(const floatx4*)src;
    floatx4 w1 = *(const floatx4*)(src + 4);

    half8 o;
#pragma unroll
    for (int i = 0; i < 4; ++i) {
        float f0 = w0[i], f1 = w1[i];
        _Float16 h0 = (_Float16)f0, h1 = (_Float16)f1;
        if (plane == 0) { o[i] = h0; o[4 + i] = h1; }
        else {
            o[i]     = (_Float16)((f0 - (float)h0) * 2048.0f);
            o[4 + i] = (_Float16)((f1 - (float)h1) * 2048.0f);
        }
    }
    *(half8*)((char*)ws + (size_t)g * 16) = o;
}

// ---------------------------------------------------------------------------
// Split-K GEMM, zero-excess regime: 256 thr / 4 waves, grid 512 = 2
// blocks/CU.  Block (sp, tg): tokens [tg*128,+128), k [sp*512,+512).
// Wave wid owns tiles {wid, wid+4} (16 tokens each), full E=64; B fragments
// read once per phase, used by both tiles.  16 phases of 32 k; W (8 KB) and
// x (16 KB) staged per phase by coalesced global_load_lds, double-buffered,
// counted vmcnt(6) + raw barriers (r2-proven protocol).  Partials written
// fragment-order, fully coalesced.
// FIX vs round 6: x chunk source offset is c*16 bytes (16 B chunks), not
// c*32 — the c*32 read ran 112 B past the x buffer (memory fault) and
// scrambled the k layout.
// ---------------------------------------------------------------------------
__global__ __launch_bounds__(256, 2) void gemm_kernel(
    const float* __restrict__ x,
    const _Float16* __restrict__ ws,
    float* __restrict__ part)
{
    __shared__ _Float16 lw[2][4096];   // 2 x 8 KB  W slices
    __shared__ float    lx[2][4096];   // 2 x 16 KB x slices

    const int tid  = threadIdx.x;
    const int lane = tid & 63;
    const int wid  = tid >> 6;         // 0..3
    const int sp   = blockIdx.x >> 7;  // k split 0..3
    const int tg   = blockIdx.x & 127; // token group
    const int t0b  = tg * TOKB;
    const int mrow = lane & 15;
    const int quad = lane >> 4;

    floatx4 acc_hh[2][4], acc_md[2][4];
#pragma unroll
    for (int tt = 0; tt < 2; ++tt)
#pragma unroll
        for (int j = 0; j < 4; ++j) {
            acc_hh[tt][j] = (floatx4)0.0f;
            acc_md[tt][j] = (floatx4)0.0f;
        }

    // W DMA source: pre-swizzled linear slices; wave wid copies 2 KB/phase.
    const char* gw0 = (const char*)ws + (size_t)(sp * NPH) * WSLICE
                    + wid * 2048 + lane * 16;
    // x DMA sources: per-lane pre-swizzled.  LDS chunk L = wid*256+i*64+lane;
    // row = L>>3, c' = L&7, source chunk c = c' ^ (row&7), 16 B per chunk.
    const char* gx[4];
#pragma unroll
    for (int i = 0; i < 4; ++i) {
        const int L   = wid * 256 + i * 64 + lane;
        const int row = L >> 3;
        const int c   = (L & 7) ^ (row & 7);
        gx[i] = (const char*)x + (size_t)(t0b + row) * (DDIM * 4)
              + sp * (KRANGE * 4) + c * 16;
    }

#define STAGE(Q, BUF)                                                          \
    {                                                                          \
        const char* gsw = gw0 + (size_t)(Q) * WSLICE;                          \
        char*       ldw = (char*)&lw[BUF][0] + wid * 2048;                     \
        __builtin_amdgcn_global_load_lds(                                      \
            (const AS1 unsigned int*)(const void*)(gsw),                       \
            (AS3 unsigned int*)(void*)(ldw), 16, 0, 0);                        \
        __builtin_amdgcn_global_load_lds(                                      \
            (const AS1 unsigned int*)(const void*)(gsw + 1024),               \
            (AS3 unsigned int*)(void*)(ldw + 1024), 16, 0, 0);                 \
        char* ldx = (char*)&lx[BUF][0] + wid * 4096;                           \
        _Pragma("unroll")                                                      \
        for (int i = 0; i < 4; ++i)                                            \
            __builtin_amdgcn_global_load_lds(                                  \
                (const AS1 unsigned int*)(const void*)(gx[i] + (size_t)(Q) * 128), \
                (AS3 unsigned int*)(void*)(ldx + i * 1024), 16, 0, 0);         \
    }

#define COMPUTE(BUF)                                                           \
    {                                                                          \
        const _Float16* wb = &lw[BUF][0];                                      \
        const float*    xb = &lx[BUF][0];                                      \
        half8 bh[4], bl[4];                                                    \
        _Pragma("unroll")                                                      \
        for (int j = 0; j < 4; ++j) {                                          \
            const int e   = j * 16 + mrow;                                     \
            const int off = e * 32 + ((quad ^ (e & 3)) << 3);                  \
            bh[j] = *(const half8*)(wb + off);                                 \
            bl[j] = *(const half8*)(wb + 2048 + off);                          \
        }                                                                      \
        _Pragma("unroll")                                                      \
        for (int tt = 0; tt < 2; ++tt) {                                       \
            const int arow = (wid + tt * 4) * 16 + mrow;                       \
            const int c0   = quad * 2;                                         \
            floatx4 X0 = *(const floatx4*)(xb + arow * 32 + ((c0 ^ (arow & 7)) << 2)); \
            floatx4 X1 = *(const floatx4*)(xb + arow * 32 + (((c0 + 1) ^ (arow & 7)) << 2)); \
            half8 a_hi, a_lo;                                                  \
            _Pragma("unroll")                                                  \
            for (int i = 0; i < 4; ++i) {                                      \
                float f0 = X0[i], f1 = X1[i];                                  \
                _Float16 h0 = (_Float16)f0, h1 = (_Float16)f1;                 \
                a_hi[i]     = h0; a_lo[i]     = (_Float16)((f0 - (float)h0) * 2048.0f); \
                a_hi[4 + i] = h1; a_lo[4 + i] = (_Float16)((f1 - (float)h1) * 2048.0f); \
            }                                                                  \
            _Pragma("unroll")                                                  \
            for (int j = 0; j < 4; ++j) {                                      \
                acc_hh[tt][j] = __builtin_amdgcn_mfma_f32_16x16x32_f16(a_hi, bh[j], acc_hh[tt][j], 0, 0, 0); \
                acc_md[tt][j] = __builtin_amdgcn_mfma_f32_16x16x32_f16(a_hi, bl[j], acc_md[tt][j], 0, 0, 0); \
                acc_md[tt][j] = __builtin_amdgcn_mfma_f32_16x16x32_f16(a_lo, bh[j], acc_md[tt][j], 0, 0, 0); \
            }                                                                  \
        }                                                                      \
    }

    // ---- prologue ----
    STAGE(0, 0)

#pragma unroll 1
    for (int q = 0; q < NPH; ++q) {
        if (q < NPH - 1) {
            STAGE(q + 1, (q + 1) & 1)
            asm volatile("s_waitcnt vmcnt(6)" ::: "memory");
        } else {
            asm volatile("s_waitcnt vmcnt(0)" ::: "memory");
        }
        __builtin_amdgcn_s_barrier();
        asm volatile("" ::: "memory");
        COMPUTE(q & 1)
        __builtin_amdgcn_s_barrier();
        asm volatile("" ::: "memory");
    }

    // ---- epilogue: coalesced fragment-order partial dump ----
    // part[sp][tl][j][lane][r], tl = tg*8 + wid + tt*4  (1 KB per (tl,j))
    float* pb = part + (size_t)sp * PSTRIDE;
#pragma unroll
    for (int tt = 0; tt < 2; ++tt) {
        const int tl = tg * 8 + wid + tt * 4;
#pragma unroll
        for (int j = 0; j < 4; ++j) {
            floatx4 v;
#pragma unroll
            for (int r = 0; r < 4; ++r)
                v[r] = acc_hh[tt][j][r] + acc_md[tt][j][r] * (1.0f / 2048.0f);
            *(floatx4*)(pb + (size_t)tl * 1024 + j * 256 + lane * 4) = v;
        }
    }
}

// ---------------------------------------------------------------------------
// Finish: 4 waves/block, wave = one 16-token tile.  Coalesced fragment-order
// reads (lane reads its own (token quad*4+r, expert j*16+m) values), sum 4
// splits + bias, then r0-proven 16-lane-group shuffle softmax + stable top-2.
// ---------------------------------------------------------------------------
__global__ __launch_bounds__(256) void finish_kernel(
    const float* __restrict__ part,
    const float* __restrict__ bias,
    float* __restrict__ out)
{
    const int tid  = threadIdx.x;
    const int lane = tid & 63;
    const int wid  = tid >> 6;
    const int tl   = blockIdx.x * 4 + wid;   // tile 0..1023
    const int mrow = lane & 15;
    const int quad = lane >> 4;

    float lg[4][4];
#pragma unroll
    for (int j = 0; j < 4; ++j) {
        floatx4 v = *(const floatx4*)(part + (size_t)tl * 1024 + j * 256 + lane * 4);
#pragma unroll
        for (int sp = 1; sp < KSPLIT; ++sp)
            v += *(const floatx4*)(part + (size_t)sp * PSTRIDE
                                   + (size_t)tl * 1024 + j * 256 + lane * 4);
        const float bj = bias[j * 16 + mrow];
#pragma unroll
        for (int r = 0; r < 4; ++r) lg[j][r] = v[r] + bj;
    }

    const int c = mrow;
#pragma unroll
    for (int r = 0; r < 4; ++r) {
        const int trow = tl * 16 + quad * 4 + r;

        float m = lg[0][r];
#pragma unroll
        for (int j = 1; j < 4; ++j) m = fmaxf(m, lg[j][r]);
#pragma unroll
        for (int off = 1; off <= 8; off <<= 1) m = fmaxf(m, __shfl_xor(m, off));

        float pj[4], s = 0.0f;
#pragma unroll
        for (int j = 0; j < 4; ++j) { pj[j] = __expf(lg[j][r] - m); s += pj[j]; }
#pragma unroll
        for (int off = 1; off <= 8; off <<= 1) s += __shfl_xor(s, off);
        const float rinv = 1.0f / s;

        // stable top-2 on logits (tie -> lower expert index)
        float v1 = -1e30f, v2 = -1e30f; int i1 = -1, i2 = -1;
#pragma unroll
        for (int j = 0; j < 4; ++j) {
            float v = lg[j][r]; int e = j * 16 + c;
            if (v > v1 || (v == v1 && e < i1)) { v2 = v1; i2 = i1; v1 = v; i1 = e; }
            else if (v > v2 || (v == v2 && e < i2)) { v2 = v; i2 = e; }
        }
#pragma unroll
        for (int off = 1; off <= 8; off <<= 1) {
            float u1 = __shfl_xor(v1, off); int q1 = __shfl_xor(i1, off);
            float u2 = __shfl_xor(v2, off); int q2 = __shfl_xor(i2, off);
            if (u1 > v1 || (u1 == v1 && q1 < i1)) {
                if (v1 > u2 || (v1 == u2 && i1 < q2)) { v2 = v1; i2 = i1; }
                else                                   { v2 = u2; i2 = q2; }
                v1 = u1; i1 = q1;
            } else {
                if (u1 > v2 || (u1 == v2 && q1 < i2)) { v2 = u1; i2 = q1; }
            }
        }

#pragma unroll
        for (int j = 0; j < 4; ++j) {
            const int col = j * 16 + c;
            const size_t o = (size_t)trow * NEXP + col;
            out[o]           = (col == i1 || col == i2) ? 1.0f : 0.0f;
            out[PSTRIDE + o] = pj[j] * rinv;
        }
    }
}

extern "C" void kernel_launch(void* const* d_in, const int* in_sizes, int n_in,
                              void* d_out, int out_size, void* d_ws, size_t ws_size,
                              hipStream_t stream) {
    const float* x = (const float*)d_in[0];   // [4,4096,2048] f32
    const float* W = (const float*)d_in[1];   // [64,2048] f32
    const float* b = (const float*)d_in[2];   // [64] f32
    (void)in_sizes; (void)n_in; (void)out_size; (void)ws_size;
    float* out = (float*)d_out;               // [masks | probs]

    _Float16* ws   = (_Float16*)d_ws;                       // 512 KB W planes
    float*    part = (float*)((char*)d_ws + PART_OFF);      // 4 x 4 MB partials

    hipLaunchKernelGGL(wconv_kernel, dim3(128), dim3(256), 0, stream, W, ws);
    hipLaunchKernelGGL(gemm_kernel, dim3(128 * KSPLIT), dim3(256), 0, stream, x, ws, part);
    hipLaunchKernelGGL(finish_kernel, dim3(256), dim3(256), 0, stream, part, b, out);
}